// Round 10
// baseline (87.772 us; speedup 1.0000x reference)
//
#include <hip/hip_runtime.h>
#include <math.h>

// LevelSelect: FCOS-style FPN level assignment.  (R6-R9 passed: absmax 0)
// Semantics locked (rounds 0-6): masked-cells-only evaluation (XLA
// select-rewrite drops out-of-mask NaN/inf), strict non-contracted f32
// per-cell math in reference op order, f64 accumulation, numpy argmin with
// STICKY FIRST-NaN, -1 for invalid boxes.
//
// R9 post-mortem: k1's 34MB full stream was the cost (not logf); only ~36k of
// 107k rows are ever needed. R9 also proved fast __logf is safe for the bulk
// focal term (absmax 0). This round: back to the single fused kernel (R7's
// CSPLIT decomposition, proven correct) with __logf on the 16-class slices;
// precise logf retained for label + NaN-deciding IoU terms. One launch, no
// ws round-trip, ~11MB gathered instead of 34MB streamed.

#define NCLS   80
#define NLEV   5
#define MAXGT  100
#define TOTAL  13343
#define BLK    256
#define CSPLIT 5            // 80 classes / 5 parts = 16 classes = 4 float4s

__device__ __forceinline__ float fadd(float a, float b) { return __fadd_rn(a, b); }
__device__ __forceinline__ float fsub(float a, float b) { return __fsub_rn(a, b); }
__device__ __forceinline__ float fmul(float a, float b) { return __fmul_rn(a, b); }
__device__ __forceinline__ float fdv (float a, float b) { return __fdiv_rn(a, b); }

struct Rect { int x1, y1, w, cells; };

__device__ __forceinline__ Rect mkrect(float b0, float b1, float b2, float b3,
                                       float st, int fd) {
    // strict f32, reference op order (unchanged from R6-R9)
    const float pb0 = fdv(b0, st), pb1 = fdv(b1, st);
    const float pb2 = fdv(b2, st), pb3 = fdv(b3, st);
    const float cx = fdv(fadd(pb0, pb2), 2.0f);
    const float cy = fdv(fadd(pb1, pb3), 2.0f);
    const float hw = fdv(fmul(fsub(pb2, pb0), 0.2f), 2.0f);
    const float hh = fdv(fmul(fsub(pb3, pb1), 0.2f), 2.0f);
    const int x1 = (int)fminf(fmaxf(floorf(fsub(cx, hw)), 0.0f), (float)(fd - 1));
    const int y1 = (int)fminf(fmaxf(floorf(fsub(cy, hh)), 0.0f), (float)(fd - 1));
    const int x2 = min(max((int)ceilf(fadd(cx, hw)), x1 + 1), fd);
    const int y2 = min(max((int)ceilf(fadd(cy, hh)), y1 + 1), fd);
    Rect r; r.x1 = x1; r.y1 = y1; r.w = x2 - x1; r.cells = (x2 - x1) * (y2 - y1);
    return r;
}

// bulk focal-neg term, fast hardware log (validated absmax-0 in R9)
__device__ __forceinline__ float focal4_fast(float4 v) {
    float s = 0.0f;
    {
        const float cp = fminf(fmaxf(v.x, 1e-6f), 1.0f - 1e-6f);
        s += 0.75f * cp * cp * (-__logf(1.0f - cp));
    }
    {
        const float cp = fminf(fmaxf(v.y, 1e-6f), 1.0f - 1e-6f);
        s += 0.75f * cp * cp * (-__logf(1.0f - cp));
    }
    {
        const float cp = fminf(fmaxf(v.z, 1e-6f), 1.0f - 1e-6f);
        s += 0.75f * cp * cp * (-__logf(1.0f - cp));
    }
    {
        const float cp = fminf(fmaxf(v.w, 1e-6f), 1.0f - 1e-6f);
        s += 0.75f * cp * cp * (-__logf(1.0f - cp));
    }
    return s;
}

__device__ __forceinline__ double waveSumD(double v) {
    #pragma unroll
    for (int o = 32; o > 0; o >>= 1) v += __shfl_down(v, o, 64);
    return v;   // lane 0 holds the wave total
}

__global__ __launch_bounds__(BLK) void level_select_kernel(
    const float* __restrict__ cls_pred,
    const float* __restrict__ regr_pred,
    const float* __restrict__ gt_boxes,
    int* __restrict__ out)
{
    const int bn  = blockIdx.x;           // 0..799, one block per (b, gt)
    const int b   = bn / MAXGT;
    const int tid = threadIdx.x;

    const float* box = gt_boxes + (size_t)bn * 5;
    const float b0 = box[0], b1 = box[1], b2 = box[2], b3 = box[3];
    const float vsum = fabsf(b0) + fabsf(b1) + fabsf(b2) + fabsf(b3);
    if (!(vsum > 0.0f)) {                 // invalid box: losses never inspected
        if (tid == 0) out[bn] = -1;
        return;
    }
    const int label = (int)box[4];

    const float* clsB = cls_pred  + (size_t)b * TOTAL * NCLS;
    const float* rgB  = regr_pred + (size_t)b * TOTAL * 4;

    const Rect r0 = mkrect(b0, b1, b2, b3,   8.0f, 100);
    const Rect r1 = mkrect(b0, b1, b2, b3,  16.0f,  50);
    const Rect r2 = mkrect(b0, b1, b2, b3,  32.0f,  25);
    const Rect r3 = mkrect(b0, b1, b2, b3,  64.0f,  13);
    const Rect r4 = mkrect(b0, b1, b2, b3, 128.0f,   7);

    const int woff1 = r0.cells * CSPLIT;
    const int woff2 = woff1 + r1.cells * CSPLIT;
    const int woff3 = woff2 + r2.cells * CSPLIT;
    const int woff4 = woff3 + r3.cells * CSPLIT;
    const int total = woff4 + r4.cells * CSPLIT;

    double a0 = 0.0, a1 = 0.0, a2 = 0.0, a3 = 0.0, a4 = 0.0;

    for (int wk = tid; wk < total; wk += BLK) {
        const int l = (wk >= woff1) + (wk >= woff2) + (wk >= woff3) + (wk >= woff4);

        const int base = (l == 0) ? 0 : (l == 1) ? woff1 : (l == 2) ? woff2
                       : (l == 3) ? woff3 : woff4;
        const Rect  rr    = (l == 0) ? r0 : (l == 1) ? r1 : (l == 2) ? r2
                          : (l == 3) ? r3 : r4;
        const float st    = (l == 0) ? 8.0f : (l == 1) ? 16.0f : (l == 2) ? 32.0f
                          : (l == 3) ? 64.0f : 128.0f;
        const int   fw    = (l == 0) ? 100 : (l == 1) ? 50 : (l == 2) ? 25
                          : (l == 3) ? 13 : 7;
        const int   start = (l == 0) ? 0 : (l == 1) ? 10000 : (l == 2) ? 12500
                          : (l == 3) ? 13125 : 13294;

        const int rel  = wk - base;
        const int cell = rel / CSPLIT;            // magic-mul (const divisor)
        const int part = rel - cell * CSPLIT;
        const int cy   = cell / rr.w;
        const int x    = rr.x1 + (cell - cy * rr.w);
        const int y    = rr.y1 + cy;
        const int p    = start + y * fw + x;

        // ---- 16-class focal slice (fast log, f32 inner sum -> f64) ----
        const float4* crow = (const float4*)(clsB + (size_t)p * NCLS + part * 16);
        double val = (double)(focal4_fast(crow[0]) + focal4_fast(crow[1]) +
                              focal4_fast(crow[2]) + focal4_fast(crow[3]));

        if (part == 0) {
            // ---- label term (precise logf) ----
            const float plab = fminf(fmaxf(clsB[(size_t)p * NCLS + label], 1e-6f),
                                     1.0f - 1e-6f);
            const float neg_lab = 0.75f * plab * plab * (-logf(1.0f - plab));
            const float one_m   = 1.0f - plab;
            const float pos_lab = 0.25f * one_m * one_m * (-logf(plab));
            val += (double)pos_lab - (double)neg_lab;

            // ---- IoU term (strict f32; NaN/inf propagate into f64 sum) ----
            const float4 rp = *(const float4*)(rgB + (size_t)p * 4);
            const float sx = fmul(fadd((float)x, 0.5f), st);
            const float sy = fmul(fadd((float)y, 0.5f), st);
            const float tl = fdv(fsub(sx, b0), 4.0f);
            const float tt = fdv(fsub(sy, b1), 4.0f);
            const float tr = fdv(fsub(b2, sx), 4.0f);
            const float tb = fdv(fsub(b3, sy), 4.0f);
            const float t_area = fmul(fadd(tl, tr), fadd(tt, tb));
            const float p_area = fmul(fadd(rp.x, rp.z), fadd(rp.y, rp.w));
            const float wi = fadd(fminf(rp.x, tl), fminf(rp.z, tr));
            const float hi = fadd(fminf(rp.y, tt), fminf(rp.w, tb));
            const float ai = fmul(wi, hi);
            const float num = fadd(ai, 1.0f);
            const float den = fadd(fsub(fadd(t_area, p_area), ai), 1.0f);
            val += (double)(-logf(fdv(num, den)));
        }

        a0 += (l == 0) ? val : 0.0;
        a1 += (l == 1) ? val : 0.0;
        a2 += (l == 2) ? val : 0.0;
        a3 += (l == 3) ? val : 0.0;
        a4 += (l == 4) ? val : 0.0;
    }

    // ---- block reduction: wave shuffles, then LDS across 4 waves ----
    a0 = waveSumD(a0); a1 = waveSumD(a1); a2 = waveSumD(a2);
    a3 = waveSumD(a3); a4 = waveSumD(a4);

    __shared__ double s_red[BLK / 64][NLEV];
    const int wave = tid >> 6, lane = tid & 63;
    if (lane == 0) {
        s_red[wave][0] = a0; s_red[wave][1] = a1; s_red[wave][2] = a2;
        s_red[wave][3] = a3; s_red[wave][4] = a4;
    }
    __syncthreads();

    if (tid == 0) {
        double lv[NLEV];
        const int cellsArr[NLEV] = {r0.cells, r1.cells, r2.cells, r3.cells, r4.cells};
        #pragma unroll
        for (int l = 0; l < NLEV; ++l) {
            double t = 0.0;
            #pragma unroll
            for (int w = 0; w < BLK / 64; ++w) t += s_red[w][l];
            lv[l] = t / (double)cellsArr[l];
        }
        // numpy argmin: FIRST NaN sticky; else strict-< (first index on ties)
        double best = INFINITY;
        int    idx  = 0;
        bool   accNan = false;
        #pragma unroll
        for (int l = 0; l < NLEV; ++l) {
            const double v = lv[l];
            if (!accNan && (isnan(v) || v < best)) {
                best = v; idx = l; accNan = isnan(v);
            }
        }
        out[bn] = idx;
    }
}

extern "C" void kernel_launch(void* const* d_in, const int* in_sizes, int n_in,
                              void* d_out, int out_size, void* d_ws, size_t ws_size,
                              hipStream_t stream) {
    (void)d_ws; (void)ws_size; (void)out_size;
    const float* cls_pred  = (const float*)d_in[0];
    const float* regr_pred = (const float*)d_in[1];
    const float* gt_boxes  = (const float*)d_in[3];
    for (int i = 0; i < n_in; ++i) {   // defensive mapping by element count
        if      (in_sizes[i] == 8 * TOTAL * NCLS) cls_pred  = (const float*)d_in[i];
        else if (in_sizes[i] == 8 * TOTAL * 4)    regr_pred = (const float*)d_in[i];
        else if (in_sizes[i] == 8 * MAXGT * 5)    gt_boxes  = (const float*)d_in[i];
    }
    int* out = (int*)d_out;

    level_select_kernel<<<8 * MAXGT, BLK, 0, stream>>>(cls_pred, regr_pred, gt_boxes, out);
}